// Round 10
// baseline (26.080 us; speedup 1.0000x reference)
//
#include <hip/hip_runtime.h>
#include <hip/hip_bf16.h>

constexpr int L_LEN = 4096;
constexpr int CH = 8;          // channels
constexpr int S_SAMPLES = 256; // continuous start samples
constexpr int K_SAMP = 32;     // shapelet samples
constexpr int NSHAPE = 16;
constexpr int NB = 32;         // batch
constexpr int NOCT = 8;        // 8-way k split (one wave each)
constexpr int THREADS = 512;   // b(32) x rowsel(2) x oct(8)

typedef float v2f __attribute__((ext_vector_type(2)));

__device__ __forceinline__ v2f bfpair(unsigned u) {
    v2f r;
    r.x = __uint_as_float(u << 16);
    r.y = __uint_as_float(u & 0xffff0000u);
    return r;
}
__device__ __forceinline__ unsigned short f2bf(float f) {
    unsigned u = __float_as_uint(f);
    u = (u + 0x7fffu + ((u >> 16) & 1u)) >> 16;   // RNE (inputs finite)
    return (unsigned short)u;
}

// path (B,L,C) f32 -> ws (L,B,C) bf16-packed; reads contiguous, writes 16B
// scattered into the L2-resident 2MB buffer.
__global__ __launch_bounds__(256) void transpose_kernel(const float4* __restrict__ src,
                                                        uint4* __restrict__ dst) {
    const int t = blockIdx.x * 256 + threadIdx.x;  // 131072 = L*B
    const int l = t & (L_LEN - 1);
    const int b = t >> 12;
    const float4 f0 = src[(b * L_LEN + l) * 2 + 0];
    const float4 f1 = src[(b * L_LEN + l) * 2 + 1];
    uint4 o;
    o.x = (unsigned)f2bf(f0.x) | ((unsigned)f2bf(f0.y) << 16);
    o.y = (unsigned)f2bf(f0.z) | ((unsigned)f2bf(f0.w) << 16);
    o.z = (unsigned)f2bf(f1.x) | ((unsigned)f2bf(f1.y) << 16);
    o.w = (unsigned)f2bf(f1.z) | ((unsigned)f2bf(f1.w) << 16);
    dst[l * NB + b] = o;
}

// One block per (p, s). tid bits: [0:4]=b, [5]=rowsel (idx vs idx+1), [6:8]=oct.
// Each per-wave load = ONE contiguous 1KB segment: lanes 0-31 row idx,
// lanes 32-63 row idx+1. Channel halves exchanged via shfl_xor(32).
__global__ __launch_bounds__(THREADS) void shapelet_min_kernel(
    const uint4* __restrict__ wst,       // (L, B, C/2) bf16-packed path
    const float* __restrict__ lengths,   // (NSHAPE)
    const float* __restrict__ shapelets, // (NSHAPE, K, C)
    float* __restrict__ partial)         // (NSHAPE, S, NB) integrals
{
    __shared__ v2f sh2[K_SAMP][5];       // 4 pairs + 8B pad per row
    __shared__ float sred[NOCT][NB];

    const int s      = blockIdx.y;
    const int p      = blockIdx.x;
    const int tid    = threadIdx.x;
    const int b      = tid & (NB - 1);
    const int rowsel = (tid >> 5) & 1;
    const int oct    = tid >> 6;                  // 0..7, wave-uniform

    if (tid < K_SAMP * CH)
        ((float*)&sh2[tid >> 3][0])[tid & 7] = shapelets[s * K_SAMP * CH + tid];
    __syncthreads();

    const float len   = fminf(fmaxf(lengths[s], 0.01f), 512.0f);
    const float start = ((float)p / (float)(S_SAMPLES - 1)) * ((float)(L_LEN - 1) - len);
    const float step  = len * (1.0f / (float)(K_SAMP - 1));
    const int   k0    = oct * (K_SAMP / NOCT);    // 0,4,...,28
    const int   jb    = rowsel * 2;               // my channel pairs: jb, jb+1

    v2f dprev0, dprev1;
    dprev0.x = 0.f; dprev0.y = 0.f; dprev1.x = 0.f; dprev1.y = 0.f;
    float sqprev = 0.f, segsum = 0.f;

    #pragma unroll
    for (int i = 0; i <= K_SAMP / NOCT; ++i) {    // 5 samples
        const int k  = k0 + i;
        const int kk = min(k, K_SAMP - 1);
        const float q = start + (float)kk * step; // q >= 0 so (int)q == floor
        const int idx = min((int)q, L_LEN - 2);
        const float r = q - (float)idx;

        // single contiguous 1KB per wave: [idx*512, idx*512+1024)
        const uint4 O = wst[(idx + rowsel) * NB + b];

        // exchange: rowsel0 receives partner's C ch0-3; rowsel1 receives A ch4-7
        const unsigned sx = rowsel ? O.x : O.z;
        const unsigned sy = rowsel ? O.y : O.w;
        const unsigned px = (unsigned)__shfl_xor((int)sx, 32);
        const unsigned py = (unsigned)__shfl_xor((int)sy, 32);
        const unsigned own0 = rowsel ? O.z : O.x;
        const unsigned own1 = rowsel ? O.w : O.y;
        // samp = A + r(C-A) == own + r''(recv-own), r'' = rowsel ? 1-r : r
        const float rs = rowsel ? (1.0f - r) : r;

        const v2f O0 = bfpair(own0), O1 = bfpair(own1);
        const v2f R0 = bfpair(px),   R1 = bfpair(py);
        v2f rv; rv.x = rs; rv.y = rs;
        const v2f samp0 = O0 + rv * (R0 - O0);
        const v2f samp1 = O1 + rv * (R1 - O1);
        const v2f d0 = samp0 - sh2[kk][jb];
        const v2f d1 = samp1 - sh2[kk][jb + 1];
        const v2f sqv  = d0 * d0 + d1 * d1;
        const v2f dotv = dprev0 * d0 + dprev1 * d1;
        const float sq = sqv.x + sqv.y;
        if (i > 0) {
            const float dot = dotv.x + dotv.y;
            const float w = (k <= K_SAMP - 1) ? 1.0f : 0.0f;
            segsum += w * (sqprev + dot + sq);
        }
        sqprev = sq;
        dprev0 = d0; dprev1 = d1;
    }

    // combine channel halves (lane bit 5)
    segsum += __shfl_xor(segsum, 32);
    if (!rowsel) sred[oct][b] = segsum;
    __syncthreads();

    if (tid < NB) {
        float tot = 0.f;
        #pragma unroll
        for (int o = 0; o < NOCT; ++o) tot += sred[o][tid];
        float integral = len * (1.0f / (3.0f * (float)(K_SAMP - 1))) * tot;
        partial[(s * S_SAMPLES + p) * NB + tid] = fmaxf(integral, 0.0f);
    }
}

// one block per shapelet; 256 threads = b(32) x chunk(8); min over 256 p + sqrt
__global__ __launch_bounds__(256) void shapelet_finalize_kernel(
    const float* __restrict__ partial, float* __restrict__ out)
{
    __shared__ float fred[8][NB];
    const int s     = blockIdx.x;
    const int tid   = threadIdx.x;
    const int b     = tid & (NB - 1);
    const int chunk = tid >> 5;                   // 0..7
    float m = 3.4e38f;
    #pragma unroll
    for (int j = 0; j < S_SAMPLES / 8; ++j) {
        const int p = chunk * (S_SAMPLES / 8) + j;
        m = fminf(m, partial[(s * S_SAMPLES + p) * NB + b]);
    }
    fred[chunk][b] = m;
    __syncthreads();
    if (tid < NB) {
        float mm = fred[0][tid];
        #pragma unroll
        for (int j = 1; j < 8; ++j) mm = fminf(mm, fred[j][tid]);
        out[tid * NSHAPE + s] = sqrtf(fmaxf(mm, 1e-12f));
    }
}

extern "C" void kernel_launch(void* const* d_in, const int* in_sizes, int n_in,
                              void* d_out, int out_size, void* d_ws, size_t ws_size,
                              hipStream_t stream) {
    // inputs: times (L), path (B,L,C), lengths (NSHAPE), shapelets (NSHAPE,K,C)
    const float* path      = (const float*)d_in[1];
    const float* lengths   = (const float*)d_in[2];
    const float* shapelets = (const float*)d_in[3];
    float* out = (float*)d_out;

    uint4* wst     = (uint4*)d_ws;                                        // 2 MB
    float* partial = (float*)((char*)d_ws + (size_t)L_LEN * NB * 16);     // 512 KB

    transpose_kernel<<<L_LEN * NB / 256, 256, 0, stream>>>(
        (const float4*)path, wst);
    dim3 grid(S_SAMPLES, NSHAPE);
    shapelet_min_kernel<<<grid, THREADS, 0, stream>>>(wst, lengths, shapelets, partial);
    shapelet_finalize_kernel<<<NSHAPE, 256, 0, stream>>>(partial, out);
}

// Round 11
// 25.864 us; speedup vs baseline: 1.0083x; 1.0083x over previous
//
#include <hip/hip_runtime.h>
#include <hip/hip_bf16.h>

constexpr int L_LEN = 4096;
constexpr int CH = 8;          // channels
constexpr int S_SAMPLES = 256; // continuous start samples
constexpr int K_SAMP = 32;     // shapelet samples
constexpr int NSHAPE = 16;
constexpr int NB = 32;         // batch
constexpr int NPB = 2;                  // p values per block
constexpr int NPBLK = S_SAMPLES / NPB;  // 128 p-blocks
constexpr int THREADS = 512;            // b(32) x half(2) x quarter(4) x pl(2)

typedef float v2f __attribute__((ext_vector_type(2)));

__device__ __forceinline__ v2f bfpair(unsigned u) {
    v2f r;
    r.x = __uint_as_float(u << 16);
    r.y = __uint_as_float(u & 0xffff0000u);
    return r;
}
__device__ __forceinline__ unsigned short f2bf(float f) {
    unsigned u = __float_as_uint(f);
    u = (u + 0x7fffu + ((u >> 16) & 1u)) >> 16;   // RNE (inputs finite)
    return (unsigned short)u;
}

// path (B,L,C) f32 -> pair-duplicated bf16 layout:
// buf entry l (1KB = 64 uint4): [l*64 + 0*32 + b]  = {l.c0c1, l.c2c3, (l+1).c0c1, (l+1).c2c3}
//                               [l*64 + 1*32 + b]  = {l.c4c5, l.c6c7, (l+1).c4c5, (l+1).c6c7}
// One 16B lane-load then serves rows idx AND idx+1 for 4 channels.
__global__ __launch_bounds__(256) void transpose_kernel(const float4* __restrict__ src,
                                                        uint4* __restrict__ dst) {
    const int t = blockIdx.x * 256 + threadIdx.x;  // 131072 = L*B
    const int l = t & (L_LEN - 1);
    const int b = t >> 12;
    const int ln = min(l + 1, L_LEN - 1);          // entry L-1 never read; stay in-bounds
    const float4 f0 = src[(b * L_LEN + l) * 2 + 0];   // row l   c0-3
    const float4 f1 = src[(b * L_LEN + l) * 2 + 1];   // row l   c4-7
    const float4 g0 = src[(b * L_LEN + ln) * 2 + 0];  // row l+1 c0-3
    const float4 g1 = src[(b * L_LEN + ln) * 2 + 1];  // row l+1 c4-7
    uint4 w0, w1;
    w0.x = (unsigned)f2bf(f0.x) | ((unsigned)f2bf(f0.y) << 16);
    w0.y = (unsigned)f2bf(f0.z) | ((unsigned)f2bf(f0.w) << 16);
    w0.z = (unsigned)f2bf(g0.x) | ((unsigned)f2bf(g0.y) << 16);
    w0.w = (unsigned)f2bf(g0.z) | ((unsigned)f2bf(g0.w) << 16);
    w1.x = (unsigned)f2bf(f1.x) | ((unsigned)f2bf(f1.y) << 16);
    w1.y = (unsigned)f2bf(f1.z) | ((unsigned)f2bf(f1.w) << 16);
    w1.z = (unsigned)f2bf(g1.x) | ((unsigned)f2bf(g1.y) << 16);
    w1.w = (unsigned)f2bf(g1.z) | ((unsigned)f2bf(g1.w) << 16);
    dst[l * 64 + b]      = w0;
    dst[l * 64 + 32 + b] = w1;
}

// tid bits: [0:4]=b, [5]=half (channels 0-3 vs 4-7), [6:7]=quarter, [8]=pl.
// Per sample: ONE 16B lane-load; wave touches one contiguous 1KB segment.
__global__ __launch_bounds__(THREADS) void shapelet_min_kernel(
    const uint4* __restrict__ buf,       // pair-duplicated bf16 path (4MB)
    const float* __restrict__ lengths,   // (NSHAPE)
    const float* __restrict__ shapelets, // (NSHAPE, K, C)
    float* __restrict__ partial)         // (NSHAPE, NPBLK, NB)
{
    __shared__ v2f sh2[K_SAMP][5];       // 4 pairs + 8B pad (broadcast reads)
    __shared__ float sred[NPB][4][NB];   // [pl][quarter][b]

    const int s    = blockIdx.y;
    const int tid  = threadIdx.x;
    const int b    = tid & (NB - 1);
    const int half = (tid >> 5) & 1;
    const int qtr  = (tid >> 6) & 3;
    const int pl   = tid >> 8;                    // 0..1
    const int p    = blockIdx.x * NPB + pl;       // 0..255

    if (tid < K_SAMP * CH)
        ((float*)&sh2[tid >> 3][0])[tid & 7] = shapelets[s * K_SAMP * CH + tid];
    __syncthreads();

    const float len   = fminf(fmaxf(lengths[s], 0.01f), 512.0f);
    const float start = ((float)p / (float)(S_SAMPLES - 1)) * ((float)(L_LEN - 1) - len);
    const float step  = len * (1.0f / (float)(K_SAMP - 1));
    const int   k0    = qtr * (K_SAMP / 4);       // 0, 8, 16, 24
    const int   jb    = half * 2;                 // my shapelet pairs: jb, jb+1
    const int   lofs  = half * 32 + b;            // lane offset within a 64-uint4 entry

    v2f dprev0, dprev1;
    dprev0.x = 0.f; dprev0.y = 0.f; dprev1.x = 0.f; dprev1.y = 0.f;
    float sqprev = 0.f, segsum = 0.f;

    #pragma unroll
    for (int i = 0; i <= K_SAMP / 4; ++i) {       // 9 samples, 8 segments
        const int k  = k0 + i;
        const int kk = min(k, K_SAMP - 1);
        const float q = start + (float)kk * step; // q >= 0 so (int)q == floor
        const int idx = min((int)q, L_LEN - 2);
        const float r = q - (float)idx;

        const uint4 V = buf[idx * 64 + lofs];     // {P01,P23,N01,N23} for my 4 ch
        const v2f P0 = bfpair(V.x), P1 = bfpair(V.y);
        const v2f N0 = bfpair(V.z), N1 = bfpair(V.w);

        v2f rv; rv.x = r; rv.y = r;
        const v2f samp0 = P0 + rv * (N0 - P0);
        const v2f samp1 = P1 + rv * (N1 - P1);
        const v2f d0 = samp0 - sh2[kk][jb];
        const v2f d1 = samp1 - sh2[kk][jb + 1];
        const v2f sqv  = d0 * d0 + d1 * d1;
        const v2f dotv = dprev0 * d0 + dprev1 * d1;
        const float sq = sqv.x + sqv.y;
        if (i > 0) {
            const float dot = dotv.x + dotv.y;
            const float w = (k <= K_SAMP - 1) ? 1.0f : 0.0f;
            segsum += w * (sqprev + dot + sq);
        }
        sqprev = sq;
        dprev0 = d0; dprev1 = d1;
    }

    // combine channel halves (lane bit 5, same wave)
    segsum += __shfl_xor(segsum, 32);
    if ((tid & 32) == 0) sred[pl][qtr][b] = segsum;
    __syncthreads();

    if (tid < 64) {
        const int bb  = tid & (NB - 1);
        const int plx = tid >> 5;                 // 0..1
        const float tot = sred[plx][0][bb] + sred[plx][1][bb] +
                          sred[plx][2][bb] + sred[plx][3][bb];
        float integral = len * (1.0f / (3.0f * (float)(K_SAMP - 1))) * tot;
        integral = fmaxf(integral, 0.0f);
        // min over the block's two p values (lane bit 5)
        const float m = fminf(integral, __shfl_xor(integral, 32));
        if (tid < NB)
            partial[(s * NPBLK + blockIdx.x) * NB + bb] = m;
    }
}

// one block per shapelet; 256 threads = b(32) x chunk(8)
__global__ __launch_bounds__(256) void shapelet_finalize_kernel(
    const float* __restrict__ partial, float* __restrict__ out)
{
    __shared__ float fred[8][NB];
    const int s     = blockIdx.x;
    const int tid   = threadIdx.x;
    const int b     = tid & (NB - 1);
    const int chunk = tid >> 5;                   // 0..7
    float m = 3.4e38f;
    #pragma unroll
    for (int j = 0; j < NPBLK / 8; ++j) {
        const int pb = chunk * (NPBLK / 8) + j;
        m = fminf(m, partial[(s * NPBLK + pb) * NB + b]);
    }
    fred[chunk][b] = m;
    __syncthreads();
    if (tid < NB) {
        float mm = fred[0][tid];
        #pragma unroll
        for (int j = 1; j < 8; ++j) mm = fminf(mm, fred[j][tid]);
        out[tid * NSHAPE + s] = sqrtf(fmaxf(mm, 1e-12f));
    }
}

extern "C" void kernel_launch(void* const* d_in, const int* in_sizes, int n_in,
                              void* d_out, int out_size, void* d_ws, size_t ws_size,
                              hipStream_t stream) {
    // inputs: times (L), path (B,L,C), lengths (NSHAPE), shapelets (NSHAPE,K,C)
    const float* path      = (const float*)d_in[1];
    const float* lengths   = (const float*)d_in[2];
    const float* shapelets = (const float*)d_in[3];
    float* out = (float*)d_out;

    uint4* buf     = (uint4*)d_ws;                                        // 4 MB
    float* partial = (float*)((char*)d_ws + (size_t)L_LEN * NB * 32);     // 256 KB

    transpose_kernel<<<L_LEN * NB / 256, 256, 0, stream>>>(
        (const float4*)path, buf);
    dim3 grid(NPBLK, NSHAPE);
    shapelet_min_kernel<<<grid, THREADS, 0, stream>>>(buf, lengths, shapelets, partial);
    shapelet_finalize_kernel<<<NSHAPE, 256, 0, stream>>>(partial, out);
}

// Round 12
// 19.479 us; speedup vs baseline: 1.3389x; 1.3278x over previous
//
#include <hip/hip_runtime.h>
#include <hip/hip_bf16.h>

constexpr int L_LEN = 4096;
constexpr int CH = 8;          // channels
constexpr int S_SAMPLES = 256; // continuous start samples
constexpr int K_SAMP = 32;     // shapelet samples
constexpr int NSHAPE = 16;
constexpr int NB = 32;         // batch
constexpr int NPB = 4;                  // p values per block
constexpr int NPBLK = S_SAMPLES / NPB;  // 64 p-blocks
constexpr int THREADS = 512;            // b(32) x quarter(4) x pl(4)

typedef _Float16 half2_t __attribute__((ext_vector_type(2)));

__device__ __forceinline__ half2_t h2(unsigned u) {
    return __builtin_bit_cast(half2_t, u);
}
__device__ __forceinline__ unsigned pack2(float a, float b) {
    half2_t h; h[0] = (_Float16)a; h[1] = (_Float16)b;
    return __builtin_bit_cast(unsigned, h);
}
__device__ __forceinline__ float fdot2acc(half2_t a, half2_t b, float c) {
#if __has_builtin(__builtin_amdgcn_fdot2)
    return __builtin_amdgcn_fdot2(a, b, c, false);
#else
    return c + (float)a[0] * (float)b[0] + (float)a[1] * (float)b[1];
#endif
}

// path (B,L,C) f32 -> ws (L,B,C) f16-packed; reads coalesced (lanes = consecutive l),
// writes 16B @ 512B stride into the L2-resident 2MB buffer (cheap).
__global__ __launch_bounds__(256) void transpose_kernel(const float4* __restrict__ src,
                                                        uint4* __restrict__ dst) {
    const int t = blockIdx.x * 256 + threadIdx.x;  // 131072 = L*B
    const int l = t & (L_LEN - 1);
    const int b = t >> 12;
    const float4 f0 = src[(b * L_LEN + l) * 2 + 0];
    const float4 f1 = src[(b * L_LEN + l) * 2 + 1];
    uint4 o;
    o.x = pack2(f0.x, f0.y);
    o.y = pack2(f0.z, f0.w);
    o.z = pack2(f1.x, f1.y);
    o.w = pack2(f1.z, f1.w);
    dst[l * NB + b] = o;
}

// tid bits: [0:4]=b, [5]=q_lo, [6]=q_hi, [7:8]=pl  (quarter = bits 5:6)
__global__ __launch_bounds__(THREADS) void shapelet_min_kernel(
    const uint4* __restrict__ wst,       // (L, B, C/2) f16-packed path
    const float* __restrict__ lengths,   // (NSHAPE)
    const float* __restrict__ shapelets, // (NSHAPE, K, C)
    float* __restrict__ partial)         // (NSHAPE, NPBLK, NB)
{
    __shared__ uint4 shsm[K_SAMP];       // shapelet rows as 8 packed f16
    __shared__ float sred[NPB][2][NB];   // [pl][q_hi][b]
    __shared__ float cand[2][NB];

    const int s       = blockIdx.y;
    const int tid     = threadIdx.x;
    const int b       = tid & (NB - 1);
    const int q_hi    = (tid >> 6) & 1;
    const int pl      = tid >> 7;                  // 0..3
    const int p       = blockIdx.x * NPB + pl;     // 0..255

    if (tid < K_SAMP * CH / 2)
        ((unsigned*)shsm)[tid] = pack2(shapelets[s * K_SAMP * CH + 2 * tid],
                                       shapelets[s * K_SAMP * CH + 2 * tid + 1]);
    __syncthreads();

    const float len   = fminf(fmaxf(lengths[s], 0.01f), 512.0f);
    const float start = ((float)p / (float)(S_SAMPLES - 1)) * ((float)(L_LEN - 1) - len);
    const float step  = len * (1.0f / (float)(K_SAMP - 1));
    const int   k0    = ((tid >> 5) & 3) * (K_SAMP / 4);    // 0, 8, 16, 24

    half2_t dprev0, dprev1, dprev2, dprev3;
    dprev0 = dprev1 = dprev2 = dprev3 = h2(0u);
    float sqprev = 0.f, segsum = 0.f;

    #pragma unroll
    for (int i = 0; i <= K_SAMP / 4; ++i) {       // 9 samples, 8 segments
        const int k  = k0 + i;
        const int kk = min(k, K_SAMP - 1);
        const float q = start + (float)kk * step; // q >= 0 so (int)q == floor
        const int idx = min((int)q, L_LEN - 2);
        const float r = q - (float)idx;
        const int base = idx * NB + b;
        const uint4 A = wst[base];
        const uint4 C = wst[base + NB];
        const uint4 SH = shsm[kk];

        const _Float16 hr = (_Float16)r;
        half2_t rr; rr[0] = hr; rr[1] = hr;

        float sq = 0.f, dot = 0.f;
        {
            const half2_t P = h2(A.x), N = h2(C.x);
            const half2_t d = P + rr * (N - P) - h2(SH.x);
            sq  = fdot2acc(d, d, sq);
            dot = fdot2acc(dprev0, d, dot);
            dprev0 = d;
        }
        {
            const half2_t P = h2(A.y), N = h2(C.y);
            const half2_t d = P + rr * (N - P) - h2(SH.y);
            sq  = fdot2acc(d, d, sq);
            dot = fdot2acc(dprev1, d, dot);
            dprev1 = d;
        }
        {
            const half2_t P = h2(A.z), N = h2(C.z);
            const half2_t d = P + rr * (N - P) - h2(SH.z);
            sq  = fdot2acc(d, d, sq);
            dot = fdot2acc(dprev2, d, dot);
            dprev2 = d;
        }
        {
            const half2_t P = h2(A.w), N = h2(C.w);
            const half2_t d = P + rr * (N - P) - h2(SH.w);
            sq  = fdot2acc(d, d, sq);
            dot = fdot2acc(dprev3, d, dot);
            dprev3 = d;
        }

        if (i > 0) {
            const float w = (k <= K_SAMP - 1) ? 1.0f : 0.0f;
            segsum += w * (sqprev + dot + sq);
        }
        sqprev = sq;
    }

    // combine quarter pairs (lane bit 5, same wave)
    segsum += __shfl_xor(segsum, 32);
    if ((tid & 32) == 0) sred[pl][q_hi][b] = segsum;
    __syncthreads();

    // integral per (pl, b), then min over the block's 4 p values
    if (tid < 128) {
        const int bb  = tid & (NB - 1);
        const int plx = tid >> 5;                  // 0..3
        const float tot = sred[plx][0][bb] + sred[plx][1][bb];
        float integral = len * (1.0f / (3.0f * (float)(K_SAMP - 1))) * tot;
        integral = fmaxf(integral, 0.0f);
        const float m1 = fminf(integral, __shfl_xor(integral, 32)); // pl pairs
        if ((tid & 32) == 0) cand[tid >> 6][bb] = m1;
    }
    __syncthreads();
    if (tid < NB)
        partial[(s * NPBLK + blockIdx.x) * NB + tid] = fminf(cand[0][tid], cand[1][tid]);
}

// one block per shapelet; 256 threads = b(32) x chunk(8)
__global__ __launch_bounds__(256) void shapelet_finalize_kernel(
    const float* __restrict__ partial, float* __restrict__ out)
{
    __shared__ float fred[8][NB];
    const int s     = blockIdx.x;
    const int tid   = threadIdx.x;
    const int b     = tid & (NB - 1);
    const int chunk = tid >> 5;                   // 0..7
    float m = 3.4e38f;
    #pragma unroll
    for (int j = 0; j < NPBLK / 8; ++j) {
        const int pb = chunk * (NPBLK / 8) + j;
        m = fminf(m, partial[(s * NPBLK + pb) * NB + b]);
    }
    fred[chunk][b] = m;
    __syncthreads();
    if (tid < NB) {
        float mm = fred[0][tid];
        #pragma unroll
        for (int j = 1; j < 8; ++j) mm = fminf(mm, fred[j][tid]);
        out[tid * NSHAPE + s] = sqrtf(fmaxf(mm, 1e-12f));
    }
}

extern "C" void kernel_launch(void* const* d_in, const int* in_sizes, int n_in,
                              void* d_out, int out_size, void* d_ws, size_t ws_size,
                              hipStream_t stream) {
    // inputs: times (L), path (B,L,C), lengths (NSHAPE), shapelets (NSHAPE,K,C)
    const float* path      = (const float*)d_in[1];
    const float* lengths   = (const float*)d_in[2];
    const float* shapelets = (const float*)d_in[3];
    float* out = (float*)d_out;

    uint4* wst     = (uint4*)d_ws;                                        // 2 MB
    float* partial = (float*)((char*)d_ws + (size_t)L_LEN * NB * 16);     // 16 KB

    transpose_kernel<<<L_LEN * NB / 256, 256, 0, stream>>>(
        (const float4*)path, wst);
    dim3 grid(NPBLK, NSHAPE);
    shapelet_min_kernel<<<grid, THREADS, 0, stream>>>(wst, lengths, shapelets, partial);
    shapelet_finalize_kernel<<<NSHAPE, 256, 0, stream>>>(partial, out);
}

// Round 13
// 19.476 us; speedup vs baseline: 1.3391x; 1.0002x over previous
//
#include <hip/hip_runtime.h>
#include <hip/hip_bf16.h>

constexpr int L_LEN = 4096;
constexpr int CH = 8;          // channels
constexpr int S_SAMPLES = 256; // continuous start samples
constexpr int K_SAMP = 32;     // shapelet samples
constexpr int NSHAPE = 16;
constexpr int NB = 32;         // batch
constexpr int NPB = 4;                  // p values per block
constexpr int NPBLK = S_SAMPLES / NPB;  // 64 p-blocks
constexpr int THREADS = 512;            // b(32) x quarter(4) x pl(4)

typedef _Float16 half2_t __attribute__((ext_vector_type(2)));

__device__ __forceinline__ half2_t h2(unsigned u) {
    return __builtin_bit_cast(half2_t, u);
}
__device__ __forceinline__ unsigned pack2(float a, float b) {
    half2_t h; h[0] = (_Float16)a; h[1] = (_Float16)b;
    return __builtin_bit_cast(unsigned, h);
}
__device__ __forceinline__ float fdot2acc(half2_t a, half2_t b, float c) {
#if __has_builtin(__builtin_amdgcn_fdot2)
    return __builtin_amdgcn_fdot2(a, b, c, false);
#else
    return c + (float)a[0] * (float)b[0] + (float)a[1] * (float)b[1];
#endif
}

// path (B,L,C) f32 -> ws (L,B,C) f16-packed; 2 b-rows per thread for ILP.
// Reads coalesced in l; writes 16B @ 512B stride into L2-resident 2MB buffer.
__global__ __launch_bounds__(256) void transpose_kernel(const float4* __restrict__ src,
                                                        uint4* __restrict__ dst) {
    const int t  = blockIdx.x * 256 + threadIdx.x; // 65536 = L * B/2
    const int l  = t & (L_LEN - 1);
    const int b0 = t >> 12;                        // 0..15; handles b0 and b0+16
    const float4 f0 = src[(b0 * L_LEN + l) * 2 + 0];
    const float4 f1 = src[(b0 * L_LEN + l) * 2 + 1];
    const float4 g0 = src[((b0 + 16) * L_LEN + l) * 2 + 0];
    const float4 g1 = src[((b0 + 16) * L_LEN + l) * 2 + 1];
    uint4 o0, o1;
    o0.x = pack2(f0.x, f0.y);  o0.y = pack2(f0.z, f0.w);
    o0.z = pack2(f1.x, f1.y);  o0.w = pack2(f1.z, f1.w);
    o1.x = pack2(g0.x, g0.y);  o1.y = pack2(g0.z, g0.w);
    o1.z = pack2(g1.x, g1.y);  o1.w = pack2(g1.z, g1.w);
    dst[l * NB + b0]      = o0;
    dst[l * NB + b0 + 16] = o1;
}

// tid bits: [0:4]=b, [5]=q_lo, [6]=q_hi, [7:8]=pl  (quarter = bits 5:6)
// min-waves/EU = 8 -> forces VGPR <= 64 -> 32 waves/CU occupancy headroom.
__global__ __launch_bounds__(THREADS, 8) void shapelet_min_kernel(
    const uint4* __restrict__ wst,       // (L, B, C/2) f16-packed path
    const float* __restrict__ lengths,   // (NSHAPE)
    const float* __restrict__ shapelets, // (NSHAPE, K, C)
    float* __restrict__ partial)         // (NSHAPE, NPBLK, NB)
{
    __shared__ uint4 shsm[K_SAMP];       // shapelet rows as 8 packed f16
    __shared__ float sred[NPB][2][NB];   // [pl][q_hi][b]
    __shared__ float cand[2][NB];

    const int s       = blockIdx.y;
    const int tid     = threadIdx.x;
    const int b       = tid & (NB - 1);
    const int q_hi    = (tid >> 6) & 1;
    const int pl      = tid >> 7;                  // 0..3
    const int p       = blockIdx.x * NPB + pl;     // 0..255

    if (tid < K_SAMP * CH / 2)
        ((unsigned*)shsm)[tid] = pack2(shapelets[s * K_SAMP * CH + 2 * tid],
                                       shapelets[s * K_SAMP * CH + 2 * tid + 1]);
    __syncthreads();

    const float len   = fminf(fmaxf(lengths[s], 0.01f), 512.0f);
    const float start = ((float)p / (float)(S_SAMPLES - 1)) * ((float)(L_LEN - 1) - len);
    const float step  = len * (1.0f / (float)(K_SAMP - 1));
    const int   k0    = ((tid >> 5) & 3) * (K_SAMP / 4);    // 0, 8, 16, 24

    half2_t dprev0, dprev1, dprev2, dprev3;
    dprev0 = dprev1 = dprev2 = dprev3 = h2(0u);
    float sqprev = 0.f, segsum = 0.f;

    #pragma unroll
    for (int i = 0; i <= K_SAMP / 4; ++i) {       // 9 samples, 8 segments
        const int k  = k0 + i;
        const int kk = min(k, K_SAMP - 1);
        const float q = start + (float)kk * step; // q >= 0 so (int)q == floor
        const int idx = min((int)q, L_LEN - 2);
        const float r = q - (float)idx;
        const int base = idx * NB + b;
        const uint4 A = wst[base];
        const uint4 C = wst[base + NB];
        const uint4 SH = shsm[kk];

        const _Float16 hr = (_Float16)r;
        half2_t rr; rr[0] = hr; rr[1] = hr;

        float sq = 0.f, dot = 0.f;
        {
            const half2_t P = h2(A.x), N = h2(C.x);
            const half2_t d = P + rr * (N - P) - h2(SH.x);
            sq  = fdot2acc(d, d, sq);
            dot = fdot2acc(dprev0, d, dot);
            dprev0 = d;
        }
        {
            const half2_t P = h2(A.y), N = h2(C.y);
            const half2_t d = P + rr * (N - P) - h2(SH.y);
            sq  = fdot2acc(d, d, sq);
            dot = fdot2acc(dprev1, d, dot);
            dprev1 = d;
        }
        {
            const half2_t P = h2(A.z), N = h2(C.z);
            const half2_t d = P + rr * (N - P) - h2(SH.z);
            sq  = fdot2acc(d, d, sq);
            dot = fdot2acc(dprev2, d, dot);
            dprev2 = d;
        }
        {
            const half2_t P = h2(A.w), N = h2(C.w);
            const half2_t d = P + rr * (N - P) - h2(SH.w);
            sq  = fdot2acc(d, d, sq);
            dot = fdot2acc(dprev3, d, dot);
            dprev3 = d;
        }

        if (i > 0) {
            const float w = (k <= K_SAMP - 1) ? 1.0f : 0.0f;
            segsum += w * (sqprev + dot + sq);
        }
        sqprev = sq;
    }

    // combine quarter pairs (lane bit 5, same wave)
    segsum += __shfl_xor(segsum, 32);
    if ((tid & 32) == 0) sred[pl][q_hi][b] = segsum;
    __syncthreads();

    // integral per (pl, b), then min over the block's 4 p values
    if (tid < 128) {
        const int bb  = tid & (NB - 1);
        const int plx = tid >> 5;                  // 0..3
        const float tot = sred[plx][0][bb] + sred[plx][1][bb];
        float integral = len * (1.0f / (3.0f * (float)(K_SAMP - 1))) * tot;
        integral = fmaxf(integral, 0.0f);
        const float m1 = fminf(integral, __shfl_xor(integral, 32)); // pl pairs
        if ((tid & 32) == 0) cand[tid >> 6][bb] = m1;
    }
    __syncthreads();
    if (tid < NB)
        partial[(s * NPBLK + blockIdx.x) * NB + tid] = fminf(cand[0][tid], cand[1][tid]);
}

// one block per shapelet; 256 threads = b(32) x chunk(8)
__global__ __launch_bounds__(256) void shapelet_finalize_kernel(
    const float* __restrict__ partial, float* __restrict__ out)
{
    __shared__ float fred[8][NB];
    const int s     = blockIdx.x;
    const int tid   = threadIdx.x;
    const int b     = tid & (NB - 1);
    const int chunk = tid >> 5;                   // 0..7
    float m = 3.4e38f;
    #pragma unroll
    for (int j = 0; j < NPBLK / 8; ++j) {
        const int pb = chunk * (NPBLK / 8) + j;
        m = fminf(m, partial[(s * NPBLK + pb) * NB + b]);
    }
    fred[chunk][b] = m;
    __syncthreads();
    if (tid < NB) {
        float mm = fred[0][tid];
        #pragma unroll
        for (int j = 1; j < 8; ++j) mm = fminf(mm, fred[j][tid]);
        out[tid * NSHAPE + s] = sqrtf(fmaxf(mm, 1e-12f));
    }
}

extern "C" void kernel_launch(void* const* d_in, const int* in_sizes, int n_in,
                              void* d_out, int out_size, void* d_ws, size_t ws_size,
                              hipStream_t stream) {
    // inputs: times (L), path (B,L,C), lengths (NSHAPE), shapelets (NSHAPE,K,C)
    const float* path      = (const float*)d_in[1];
    const float* lengths   = (const float*)d_in[2];
    const float* shapelets = (const float*)d_in[3];
    float* out = (float*)d_out;

    uint4* wst     = (uint4*)d_ws;                                        // 2 MB
    float* partial = (float*)((char*)d_ws + (size_t)L_LEN * NB * 16);     // 16 KB

    transpose_kernel<<<L_LEN * NB / 2 / 256, 256, 0, stream>>>(
        (const float4*)path, wst);
    dim3 grid(NPBLK, NSHAPE);
    shapelet_min_kernel<<<grid, THREADS, 0, stream>>>(wst, lengths, shapelets, partial);
    shapelet_finalize_kernel<<<NSHAPE, 256, 0, stream>>>(partial, out);
}